// Round 7
// baseline (612.244 us; speedup 1.0000x reference)
//
#include <hip/hip_runtime.h>

#define BB 16
#define NN 2048
#define DD 128

typedef __attribute__((ext_vector_type(8))) __bf16 bf16x8;
typedef __attribute__((ext_vector_type(4))) float f32x4;
typedef __attribute__((ext_vector_type(4))) unsigned int u32x4;
typedef __attribute__((address_space(3))) unsigned int lds_u32;
typedef __attribute__((address_space(1))) const unsigned int glob_u32;

static __device__ __forceinline__ unsigned short f2b(float f) {
  union { float f; unsigned int u; } c; c.f = f;
  unsigned int u = c.u;
  unsigned int r = (u + 0x7FFFu + ((u >> 16) & 1u)) >> 16;
  return (unsigned short)r;
}
static __device__ __forceinline__ float b2f(unsigned short u) {
  union { unsigned int u; float f; } c; c.u = ((unsigned int)u) << 16;
  return c.f;
}

// ===== Tiled layouts (all K-loop staging streams are contiguous) =====
// adjTt[b][jt][kt][p=0..511]  8KB tiles; chunk p (16B) holds
//   adjT[jt*64 + (p>>3)][kt*64 + ((p&7)^((p>>3)&7))*8 + s]   (XOR swizzle baked in)
// hwTt[b][kt][p=0..1023] 16KB tiles; chunk p holds
//   hwT[e=(p>>3)][kt*64 + ((p&7)^((p>>3)&7))*8 + s]

// WT[l][e][d] = bf16(W[l][d][e])  -- 96 KB total, L2-resident afterwards
__global__ void k_wt(const float* __restrict__ W, unsigned short* __restrict__ WT) {
  __shared__ float t[64][65];
  int l = blockIdx.z, d0 = blockIdx.x * 64, e0 = blockIdx.y * 64;
  int tid = threadIdx.x;
  const float* src = W + (size_t)l * DD * DD;
  for (int p = 0; p < 16; ++p) {
    int idx = p * 256 + tid;
    int d = idx >> 6, e = idx & 63;
    t[e][d] = src[(size_t)(d0 + d) * DD + (e0 + e)];
  }
  __syncthreads();
  unsigned short* dst = WT + (size_t)l * DD * DD;
  for (int p = 0; p < 4; ++p) {
    int idx = p * 256 + tid;
    int e = idx >> 4, d4 = (idx & 15) * 4;
    ushort4 r;
    r.x = f2b(t[e][d4 + 0]); r.y = f2b(t[e][d4 + 1]);
    r.z = f2b(t[e][d4 + 2]); r.w = f2b(t[e][d4 + 3]);
    *(ushort4*)(dst + (size_t)(e0 + e) * DD + (d0 + d4)) = r;
  }
}

// x<256: transpose adj -> tiled adjTt; x>=256: layer-0 gemm1 -> tiled hwTt
__global__ __launch_bounds__(256) void k_pre(const float* __restrict__ adj,
                                             unsigned short* __restrict__ adjTt,
                                             const float* __restrict__ X,
                                             const unsigned short* __restrict__ WT,
                                             unsigned short* __restrict__ hwTt) {
  __shared__ unsigned short t2[64 * 260];  // t2[i][j] bf16, 33.3 KB
  int b = blockIdx.y, x = blockIdx.x, tid = threadIdx.x;
  if (x < 256) {
    int i_t = x >> 3, j_t = x & 7;
    int i0 = i_t * 64, j0 = j_t * 256;
    const float* src = adj + (size_t)b * NN * NN;
#pragma unroll
    for (int p = 0; p < 16; ++p) {
      int idx = p * 256 + tid;
      int i = idx >> 6, jc = (idx & 63) * 4;
      float4 v = *(const float4*)(src + (size_t)(i0 + i) * NN + (j0 + jc));
      unsigned int* d = (unsigned int*)(t2 + i * 260 + jc);
      d[0] = (unsigned int)f2b(v.x) | ((unsigned int)f2b(v.y) << 16);
      d[1] = (unsigned int)f2b(v.z) | ((unsigned int)f2b(v.w) << 16);
    }
    __syncthreads();
#pragma unroll
    for (int pp = 0; pp < 8; ++pp) {
      int idx = pp * 256 + tid;
      int sub = idx >> 9, p = idx & 511;
      int r = p >> 3, g = (p & 7) ^ (r & 7);
      union { u32x4 u; unsigned short h[8]; } ub;
#pragma unroll
      for (int s = 0; s < 8; ++s) ub.h[s] = t2[(g * 8 + s) * 260 + sub * 64 + r];
      size_t tile = ((size_t)(b * 32 + j_t * 4 + sub) * 32 + i_t) * 4096;
      *(u32x4*)(adjTt + tile + p * 8) = ub.u;
    }
  } else {
    int kt = x - 256;
    int i0 = kt * 64;
    int lane = tid & 63, w = tid >> 6;
    int q = lane >> 4, m = lane & 15;
    f32x4 acc[8];
#pragma unroll
    for (int t = 0; t < 8; ++t)
#pragma unroll
      for (int r = 0; r < 4; ++r) acc[t][r] = 0.f;
    int il = w * 16 + m;
    const float* hrow = X + ((size_t)b * NN + i0 + il) * DD;
#pragma unroll
    for (int kk = 0; kk < 4; ++kk) {
      int d0 = kk * 32 + q * 8;
      float4 h0 = *(const float4*)(hrow + d0);
      float4 h1 = *(const float4*)(hrow + d0 + 4);
      union { bf16x8 v; unsigned short s[8]; } ub;
      ub.s[0] = f2b(h0.x); ub.s[1] = f2b(h0.y); ub.s[2] = f2b(h0.z); ub.s[3] = f2b(h0.w);
      ub.s[4] = f2b(h1.x); ub.s[5] = f2b(h1.y); ub.s[6] = f2b(h1.z); ub.s[7] = f2b(h1.w);
#pragma unroll
      for (int mt = 0; mt < 8; ++mt) {
        bf16x8 af = *(const bf16x8*)(WT + (mt * 16 + m) * 128 + d0);
        acc[mt] = __builtin_amdgcn_mfma_f32_16x16x32_bf16(af, ub.v, acc[mt], 0, 0, 0);
      }
    }
    unsigned short* dst = hwTt + ((size_t)b * 32 + kt) * 8192;
#pragma unroll
    for (int mt = 0; mt < 8; ++mt)
#pragma unroll
      for (int r = 0; r < 4; ++r) {
        int e = mt * 16 + q * 4 + r;
        int p = e * 8 + ((il >> 3) ^ (e & 7));
        dst[p * 8 + (il & 7)] = f2b(acc[mt][r]);
      }
  }
}

// Staging macro: stage tile (aSrc/hSrc cursors) into buffer at nb.
#define STAGE(nb)                                                                   \
  {                                                                                 \
    _Pragma("unroll")                                                               \
    for (int it = 0; it < 2; ++it) {                                                \
      __builtin_amdgcn_global_load_lds((glob_u32*)aSrc[it],                         \
                                       (lds_u32*)((nb) + (it * 4 + w) * 512), 16, 0, 0); \
      aSrc[it] += 4096;                                                             \
    }                                                                               \
    _Pragma("unroll")                                                               \
    for (int it = 0; it < 4; ++it) {                                                \
      __builtin_amdgcn_global_load_lds((glob_u32*)hSrc[it],                         \
                                       (lds_u32*)((nb) + 4096 + (it * 4 + w) * 512), 16, 0, 0); \
      hSrc[it] += 8192;                                                             \
    }                                                                               \
  }

// ===== PROBE ROUND: K-loop repeated `reps` times (acc carried across reps, scaled
// by 1/reps before epilogue -> no DCE, ~1ulp numerics change). reps=2 makes each
// k_layer dispatch ~T+T_Kloop: (a) dur delta = 3*T_Kloop (exact split), (b) k_layer
// becomes the LONGEST dispatch -> rocprof finally shows ITS counters (FETCH_SIZE,
// MfmaUtil, VALUBusy, bank conflicts, occupancy) instead of harness fills.
__global__ __launch_bounds__(256) void k_layer(const unsigned short* __restrict__ adjTt,
                                               const unsigned short* __restrict__ hwTt,
                                               const float* __restrict__ res,
                                               const float* __restrict__ bias,
                                               const float* __restrict__ gamma,
                                               const float* __restrict__ beta,
                                               const unsigned short* __restrict__ WTn,
                                               float* __restrict__ outf,
                                               unsigned short* __restrict__ hwTnt,
                                               int doW, int reps) {
  __shared__ __align__(16) unsigned short sbuf[3 * 12288];  // 3 x (sA 4096 + sH 8192) = 72KB
  __shared__ float smu[64], srs[64];
  float* z = (float*)sbuf;  // 64x132 f32 = 33.8 KB, alias: staging dead after K-loop

  int tid = threadIdx.x;
  int lane = tid & 63, w = tid >> 6;
  int q = lane >> 4, m = lane & 15;
  int wj = w & 1, we = w >> 1;
  int b = blockIdx.y, jt = blockIdx.x, j0 = jt * 64;
  const unsigned short* At = adjTt + ((size_t)(b * 32 + jt)) * 32 * 4096;
  const unsigned short* Ht = hwTt + (size_t)b * 32 * 8192;

  f32x4 acc[2][4];
#pragma unroll
  for (int i = 0; i < 2; ++i)
#pragma unroll
    for (int j = 0; j < 4; ++j)
#pragma unroll
      for (int r = 0; r < 4; ++r) acc[i][j][r] = 0.f;

  for (int rep = 0; rep < reps; ++rep) {
    const unsigned short* aSrc[2];
    const unsigned short* hSrc[4];
#pragma unroll
    for (int it = 0; it < 2; ++it)
      aSrc[it] = At + ((it * 4 + w) * 64 + lane) * 8;
#pragma unroll
    for (int it = 0; it < 4; ++it)
      hSrc[it] = Ht + ((it * 4 + w) * 64 + lane) * 8;

    // Prologue: stage tiles 0,1; wait only for tile 0 (6 newest = tile 1 in flight)
    STAGE(sbuf);
    STAGE(sbuf + 12288);
    asm volatile("s_waitcnt vmcnt(6)" ::: "memory");
    __builtin_amdgcn_s_barrier();

    int bi = 0;
    for (int t = 0; t < 32; ++t) {
      const unsigned short* sA = sbuf + bi * 12288;
      const unsigned short* sH = sA + 4096;
      if (t < 30) {
        int nbi = bi + 2; if (nbi >= 3) nbi -= 3;
        unsigned short* nb = sbuf + nbi * 12288;
        STAGE(nb);
      }
#pragma unroll
      for (int kk = 0; kk < 2; ++kk) {
        bf16x8 af[2], bfr[4];
#pragma unroll
        for (int mt = 0; mt < 2; ++mt) {
          int r = wj * 32 + mt * 16 + m;
          int c = (kk * 4 + q) ^ (r & 7);
          af[mt] = *(const bf16x8*)(sA + r * 64 + c * 8);
        }
#pragma unroll
        for (int nt = 0; nt < 4; ++nt) {
          int r = we * 64 + nt * 16 + m;
          int c = (kk * 4 + q) ^ (r & 7);
          bfr[nt] = *(const bf16x8*)(sH + r * 64 + c * 8);
        }
#pragma unroll
        for (int mt = 0; mt < 2; ++mt)
#pragma unroll
          for (int nt = 0; nt < 4; ++nt)
            acc[mt][nt] = __builtin_amdgcn_mfma_f32_16x16x32_bf16(af[mt], bfr[nt], acc[mt][nt], 0, 0, 0);
      }
      if (t < 30) {
        asm volatile("s_waitcnt vmcnt(6)" ::: "memory");  // t+1 resident; t+2 in flight
        __builtin_amdgcn_s_barrier();
      } else if (t == 30) {
        asm volatile("s_waitcnt vmcnt(0)" ::: "memory");  // tile 31 resident
        __builtin_amdgcn_s_barrier();
      }
      bi = bi + 1; if (bi == 3) bi = 0;
    }
    __syncthreads();  // all reads of buffers done before next rep's STAGE / z alias
  }

  if (reps > 1) {
    float s = 1.0f / (float)reps;
#pragma unroll
    for (int mt = 0; mt < 2; ++mt)
#pragma unroll
      for (int nt = 0; nt < 4; ++nt)
#pragma unroll
        for (int r = 0; r < 4; ++r) acc[mt][nt][r] *= s;
  }

  // E1: spill accumulators (full-K fp32 sums) into z
#pragma unroll
  for (int mt = 0; mt < 2; ++mt)
#pragma unroll
    for (int nt = 0; nt < 4; ++nt)
#pragma unroll
      for (int r = 0; r < 4; ++r) {
        int row = wj * 32 + mt * 16 + q * 4 + r;
        int col = we * 64 + nt * 16 + m;
        z[row * 132 + col] = acc[mt][nt][r];
      }
  __syncthreads();

  // E2: z += res + bias
  size_t base = ((size_t)b * NN + j0) * DD;
#pragma unroll
  for (int p = 0; p < 4; ++p) {
    int idx = p * 256 + tid;
    int j = idx >> 4, c8 = (idx & 15) * 8;
    size_t off = (size_t)j * DD + c8;
    const float4* r4 = (const float4*)(res + base + off);
    float4 r0 = r4[0], r1 = r4[1];
    const float4* bi4 = (const float4*)(bias + c8);
    float4 b0 = bi4[0], b1 = bi4[1];
    float* zz = &z[j * 132 + c8];
    zz[0] += r0.x + b0.x; zz[1] += r0.y + b0.y;
    zz[2] += r0.z + b0.z; zz[3] += r0.w + b0.w;
    zz[4] += r1.x + b1.x; zz[5] += r1.y + b1.y;
    zz[6] += r1.z + b1.z; zz[7] += r1.w + b1.w;
  }
  __syncthreads();

  // E3: LN stats (4 threads per row, interleaved reads; 2-way bank = free)
  {
    int j = tid >> 2, s = tid & 3;
    float sum = 0.f, sq = 0.f;
#pragma unroll
    for (int k = 0; k < 32; ++k) {
      float v = z[j * 132 + s + 4 * k];
      sum += v; sq += v * v;
    }
    sum += __shfl_xor(sum, 1); sq += __shfl_xor(sq, 1);
    sum += __shfl_xor(sum, 2); sq += __shfl_xor(sq, 2);
    if (s == 0) {
      float mu = sum * (1.f / 128.f);
      float var = sq * (1.f / 128.f) - mu * mu;
      smu[j] = mu;
      srs[j] = rsqrtf(var + 1e-5f);
    }
  }
  __syncthreads();

  // E4: normalize + ReLU -> outf; keep h in z for gemm1
  {
    int e = tid & 127;
    float g = gamma[e], bt = beta[e];
#pragma unroll
    for (int p = 0; p < 32; ++p) {
      int idx = p * 256 + tid;
      int j = idx >> 7;
      float v = (z[j * 132 + e] - smu[j]) * srs[j] * g + bt;
      v = fmaxf(v, 0.f);
      outf[base + idx] = v;
      z[j * 132 + e] = v;   // same thread, same slot: no race
    }
  }
  if (!doW) return;
  __syncthreads();

  // E5: gemm1 -> tiled hwTnt tile (kt = jt); WTn fragments direct from global
  f32x4 acc2[8];
#pragma unroll
  for (int t = 0; t < 8; ++t)
#pragma unroll
    for (int r = 0; r < 4; ++r) acc2[t][r] = 0.f;
  int il = w * 16 + m;
  const float* hrow = &z[il * 132];
#pragma unroll
  for (int kk = 0; kk < 4; ++kk) {
    int d0 = kk * 32 + q * 8;
    float4 h0 = *(const float4*)(hrow + d0);
    float4 h1 = *(const float4*)(hrow + d0 + 4);
    union { bf16x8 v; unsigned short s[8]; } ub;
    ub.s[0] = f2b(h0.x); ub.s[1] = f2b(h0.y); ub.s[2] = f2b(h0.z); ub.s[3] = f2b(h0.w);
    ub.s[4] = f2b(h1.x); ub.s[5] = f2b(h1.y); ub.s[6] = f2b(h1.z); ub.s[7] = f2b(h1.w);
#pragma unroll
    for (int mt = 0; mt < 8; ++mt) {
      bf16x8 af = *(const bf16x8*)(WTn + (mt * 16 + m) * 128 + d0);
      acc2[mt] = __builtin_amdgcn_mfma_f32_16x16x32_bf16(af, ub.v, acc2[mt], 0, 0, 0);
    }
  }
  unsigned short* dst = hwTnt + ((size_t)b * 32 + jt) * 8192;
#pragma unroll
  for (int mt = 0; mt < 8; ++mt)
#pragma unroll
    for (int r = 0; r < 4; ++r) {
      int e = mt * 16 + q * 4 + r;
      int p = e * 8 + ((il >> 3) ^ (e & 7));
      dst[p * 8 + (il & 7)] = f2b(acc2[mt][r]);
    }
}

extern "C" void kernel_launch(void* const* d_in, const int* in_sizes, int n_in,
                              void* d_out, int out_size, void* d_ws, size_t ws_size,
                              hipStream_t stream) {
  const float* X   = (const float*)d_in[0];
  const float* adj = (const float*)d_in[1];
  const float* Ws  = (const float*)d_in[2];
  const float* bs  = (const float*)d_in[3];
  const float* gms = (const float*)d_in[4];
  const float* bts = (const float*)d_in[5];
  float* out = (float*)d_out;

  // ws: adjTt bf16 (134MB) | hwTt ping-pong bf16 (2 x 8.4MB) | WT bf16 (96KB)
  unsigned short* adjTt = (unsigned short*)d_ws;
  unsigned short* hwT0  = adjTt + (size_t)BB * NN * NN;
  unsigned short* hwT1  = hwT0 + (size_t)BB * DD * NN;
  unsigned short* WT    = hwT1 + (size_t)BB * DD * NN;

  k_wt<<<dim3(2, 2, 3), 256, 0, stream>>>(Ws, WT);
  k_pre<<<dim3(288, BB), 256, 0, stream>>>(adj, adjTt, X, WT, hwT0);
  for (int l = 0; l < 3; ++l) {
    const float* res = (l == 0) ? X : (const float*)out;
    const unsigned short* WTn = WT + (size_t)((l < 2) ? (l + 1) : 0) * DD * DD;
    unsigned short* hin  = (l & 1) ? hwT1 : hwT0;
    unsigned short* hout = (l & 1) ? hwT0 : hwT1;
    // reps=2: K-loop doubled (probe). dur = base + 3*T_Kloop.
    k_layer<<<dim3(NN / 64, BB), 256, 0, stream>>>(adjTt, hin, res, bs + l * DD,
                                                   gms + l * DD, bts + l * DD,
                                                   WTn, out, hout, (l < 2) ? 1 : 0, 2);
  }
}

// Round 8
// 532.722 us; speedup vs baseline: 1.1493x; 1.1493x over previous
//
#include <hip/hip_runtime.h>

#define BB 16
#define NN 2048
#define DD 128

typedef __attribute__((ext_vector_type(8))) __bf16 bf16x8;
typedef __attribute__((ext_vector_type(4))) float f32x4;
typedef __attribute__((ext_vector_type(4))) unsigned int u32x4;
typedef __attribute__((address_space(3))) unsigned int lds_u32;
typedef __attribute__((address_space(1))) const unsigned int glob_u32;

static __device__ __forceinline__ unsigned short f2b(float f) {
  union { float f; unsigned int u; } c; c.f = f;
  unsigned int u = c.u;
  unsigned int r = (u + 0x7FFFu + ((u >> 16) & 1u)) >> 16;
  return (unsigned short)r;
}
static __device__ __forceinline__ float b2f(unsigned short u) {
  union { unsigned int u; float f; } c; c.u = ((unsigned int)u) << 16;
  return c.f;
}

// ===== Tiled layouts (all K-loop staging streams are contiguous) =====
// adjTt[b][jt][kt][p=0..511]  8KB tiles; chunk p (16B) holds
//   adjT[jt*64 + (p>>3)][kt*64 + ((p&7)^((p>>3)&7))*8 + s]   (XOR swizzle baked in)
// hwTt[b][kt][p=0..1023] 16KB tiles; chunk p holds
//   hwT[e=(p>>3)][kt*64 + ((p&7)^((p>>3)&7))*8 + s]

// k_pre (merged, single launch):
//   x <  256 : adj transpose -> tiled adjTt
//   x <  288 : layer-0 gemm1 -> tiled hwTt (W staged fp32->bf16 in LDS; no WT dep)
//   x <  291 : (y==0) W[l]->WT[l][e][d] transpose-cast for k_layer E5 (l = x-288)
__global__ __launch_bounds__(256) void k_pre(const float* __restrict__ adj,
                                             unsigned short* __restrict__ adjTt,
                                             const float* __restrict__ X,
                                             const float* __restrict__ W,
                                             unsigned short* __restrict__ WT,
                                             unsigned short* __restrict__ hwTt) {
  __shared__ __align__(16) unsigned short t2[17408];  // 34.8 KB scratch, multi-use
  int b = blockIdx.y, x = blockIdx.x, tid = threadIdx.x;
  if (x < 256) {
    int i_t = x >> 3, j_t = x & 7;
    int i0 = i_t * 64, j0 = j_t * 256;
    const float* src = adj + (size_t)b * NN * NN;
#pragma unroll
    for (int p = 0; p < 16; ++p) {
      int idx = p * 256 + tid;
      int i = idx >> 6, jc = (idx & 63) * 4;
      float4 v = *(const float4*)(src + (size_t)(i0 + i) * NN + (j0 + jc));
      unsigned int* d = (unsigned int*)(t2 + i * 260 + jc);
      d[0] = (unsigned int)f2b(v.x) | ((unsigned int)f2b(v.y) << 16);
      d[1] = (unsigned int)f2b(v.z) | ((unsigned int)f2b(v.w) << 16);
    }
    __syncthreads();
#pragma unroll
    for (int pp = 0; pp < 8; ++pp) {
      int idx = pp * 256 + tid;
      int sub = idx >> 9, p = idx & 511;
      int r = p >> 3, g = (p & 7) ^ (r & 7);
      union { u32x4 u; unsigned short h[8]; } ub;
#pragma unroll
      for (int s = 0; s < 8; ++s) ub.h[s] = t2[(g * 8 + s) * 260 + sub * 64 + r];
      size_t tile = ((size_t)(b * 32 + j_t * 4 + sub) * 32 + i_t) * 4096;
      *(u32x4*)(adjTt + tile + p * 8) = ub.u;
    }
  } else if (x < 288) {
    // stage W (layer 0) as sWT[e][d] bf16, stride 136 (16B-aligned rows, 2-way bank)
    unsigned short* sWT = t2;
#pragma unroll
    for (int p = 0; p < 16; ++p) {
      int idx = p * 256 + tid;              // 4096 float4s of W[d][e]
      int d = idx >> 5, e4 = (idx & 31) * 4;
      float4 v = *(const float4*)(W + d * DD + e4);
      sWT[(e4 + 0) * 136 + d] = f2b(v.x);
      sWT[(e4 + 1) * 136 + d] = f2b(v.y);
      sWT[(e4 + 2) * 136 + d] = f2b(v.z);
      sWT[(e4 + 3) * 136 + d] = f2b(v.w);
    }
    __syncthreads();
    int kt = x - 256;
    int i0 = kt * 64;
    int lane = tid & 63, w = tid >> 6;
    int q = lane >> 4, m = lane & 15;
    f32x4 acc[8];
#pragma unroll
    for (int t = 0; t < 8; ++t)
#pragma unroll
      for (int r = 0; r < 4; ++r) acc[t][r] = 0.f;
    int il = w * 16 + m;
    const float* hrow = X + ((size_t)b * NN + i0 + il) * DD;
#pragma unroll
    for (int kk = 0; kk < 4; ++kk) {
      int d0 = kk * 32 + q * 8;
      float4 h0 = *(const float4*)(hrow + d0);
      float4 h1 = *(const float4*)(hrow + d0 + 4);
      union { bf16x8 v; unsigned short s[8]; } ub;
      ub.s[0] = f2b(h0.x); ub.s[1] = f2b(h0.y); ub.s[2] = f2b(h0.z); ub.s[3] = f2b(h0.w);
      ub.s[4] = f2b(h1.x); ub.s[5] = f2b(h1.y); ub.s[6] = f2b(h1.z); ub.s[7] = f2b(h1.w);
#pragma unroll
      for (int mt = 0; mt < 8; ++mt) {
        bf16x8 af = *(const bf16x8*)(sWT + (mt * 16 + m) * 136 + d0);
        acc[mt] = __builtin_amdgcn_mfma_f32_16x16x32_bf16(af, ub.v, acc[mt], 0, 0, 0);
      }
    }
    unsigned short* dst = hwTt + ((size_t)b * 32 + kt) * 8192;
#pragma unroll
    for (int mt = 0; mt < 8; ++mt)
#pragma unroll
      for (int r = 0; r < 4; ++r) {
        int e = mt * 16 + q * 4 + r;
        int p = e * 8 + ((il >> 3) ^ (e & 7));
        dst[p * 8 + (il & 7)] = f2b(acc[mt][r]);
      }
  } else if (b == 0) {
    // WT[l][e][d] = bf16(W[l][d][e]) -- consumed by k_layer E5 (later launches only)
    int l = x - 288;
    float (*tf)[65] = (float (*)[65])t2;
    const float* src = W + (size_t)l * DD * DD;
    unsigned short* dstw = WT + (size_t)l * DD * DD;
    for (int s = 0; s < 4; ++s) {
      int d0 = (s >> 1) * 64, e0 = (s & 1) * 64;
      __syncthreads();
      for (int p = 0; p < 16; ++p) {
        int idx = p * 256 + tid;
        int d = idx >> 6, e = idx & 63;
        tf[e][d] = src[(size_t)(d0 + d) * DD + (e0 + e)];
      }
      __syncthreads();
      for (int p = 0; p < 4; ++p) {
        int idx = p * 256 + tid;
        int e = idx >> 4, d4 = (idx & 15) * 4;
        ushort4 r;
        r.x = f2b(tf[e][d4 + 0]); r.y = f2b(tf[e][d4 + 1]);
        r.z = f2b(tf[e][d4 + 2]); r.w = f2b(tf[e][d4 + 3]);
        *(ushort4*)(dstw + (size_t)(e0 + e) * DD + (d0 + d4)) = r;
      }
    }
  }
}

// Staging macro: stage tile (aSrc/hSrc cursors) into buffer at nb.
#define STAGE(nb)                                                                   \
  {                                                                                 \
    _Pragma("unroll")                                                               \
    for (int it = 0; it < 2; ++it) {                                                \
      __builtin_amdgcn_global_load_lds((glob_u32*)aSrc[it],                         \
                                       (lds_u32*)((nb) + (it * 4 + w) * 512), 16, 0, 0); \
      aSrc[it] += 4096;                                                             \
    }                                                                               \
    _Pragma("unroll")                                                               \
    for (int it = 0; it < 4; ++it) {                                                \
      __builtin_amdgcn_global_load_lds((glob_u32*)hSrc[it],                         \
                                       (lds_u32*)((nb) + 4096 + (it * 4 + w) * 512), 16, 0, 0); \
      hSrc[it] += 8192;                                                             \
    }                                                                               \
  }

// Fused per-layer kernel: tiled staging + counted vmcnt (R6) + b-major XCD swizzle.
// Swizzle mechanism (now in-regime): each XCD owns 2 full batches -> hwTt working
// set 1 MB/XCD -> 268 MB/layer of hwT re-reads served from L2 (34 TB/s) not L3.
__global__ __launch_bounds__(256) void k_layer(const unsigned short* __restrict__ adjTt,
                                               const unsigned short* __restrict__ hwTt,
                                               const float* __restrict__ res,
                                               const float* __restrict__ bias,
                                               const float* __restrict__ gamma,
                                               const float* __restrict__ beta,
                                               const unsigned short* __restrict__ WTn,
                                               float* __restrict__ outf,
                                               unsigned short* __restrict__ hwTnt,
                                               int doW) {
  __shared__ __align__(16) unsigned short sbuf[3 * 12288];  // 3 x (sA 4096 + sH 8192) = 72KB
  __shared__ float smu[64], srs[64];
  float* z = (float*)sbuf;  // 64x132 f32 = 33.8 KB, alias: staging dead after K-loop

  int tid = threadIdx.x;
  int lane = tid & 63, w = tid >> 6;
  int q = lane >> 4, m = lane & 15;
  int wj = w & 1, we = w >> 1;
  // b-major bijective XCD swizzle (512 blocks, 512%8==0): xcd=id&7 gets 64
  // contiguous L = 2 full batches.
  int id = blockIdx.x + (blockIdx.y << 5);
  int L = (id & 7) * 64 + (id >> 3);
  int b = L >> 5, jt = L & 31, j0 = jt * 64;
  const unsigned short* At = adjTt + ((size_t)(b * 32 + jt)) * 32 * 4096;
  const unsigned short* Ht = hwTt + (size_t)b * 32 * 8192;

  const unsigned short* aSrc[2];
  const unsigned short* hSrc[4];
#pragma unroll
  for (int it = 0; it < 2; ++it)
    aSrc[it] = At + ((it * 4 + w) * 64 + lane) * 8;
#pragma unroll
  for (int it = 0; it < 4; ++it)
    hSrc[it] = Ht + ((it * 4 + w) * 64 + lane) * 8;

  f32x4 acc[2][4];
#pragma unroll
  for (int i = 0; i < 2; ++i)
#pragma unroll
    for (int j = 0; j < 4; ++j)
#pragma unroll
      for (int r = 0; r < 4; ++r) acc[i][j][r] = 0.f;

  // Prologue: stage tiles 0,1; wait only for tile 0 (6 newest = tile 1 in flight)
  STAGE(sbuf);
  STAGE(sbuf + 12288);
  asm volatile("s_waitcnt vmcnt(6)" ::: "memory");
  __builtin_amdgcn_s_barrier();

  int bi = 0;
  for (int t = 0; t < 32; ++t) {
    const unsigned short* sA = sbuf + bi * 12288;
    const unsigned short* sH = sA + 4096;
    if (t < 30) {
      int nbi = bi + 2; if (nbi >= 3) nbi -= 3;
      unsigned short* nb = sbuf + nbi * 12288;
      STAGE(nb);
    }
#pragma unroll
    for (int kk = 0; kk < 2; ++kk) {
      bf16x8 af[2], bfr[4];
#pragma unroll
      for (int mt = 0; mt < 2; ++mt) {
        int r = wj * 32 + mt * 16 + m;
        int c = (kk * 4 + q) ^ (r & 7);
        af[mt] = *(const bf16x8*)(sA + r * 64 + c * 8);
      }
#pragma unroll
      for (int nt = 0; nt < 4; ++nt) {
        int r = we * 64 + nt * 16 + m;
        int c = (kk * 4 + q) ^ (r & 7);
        bfr[nt] = *(const bf16x8*)(sH + r * 64 + c * 8);
      }
#pragma unroll
      for (int mt = 0; mt < 2; ++mt)
#pragma unroll
        for (int nt = 0; nt < 4; ++nt)
          acc[mt][nt] = __builtin_amdgcn_mfma_f32_16x16x32_bf16(af[mt], bfr[nt], acc[mt][nt], 0, 0, 0);
    }
    if (t < 30) {
      asm volatile("s_waitcnt vmcnt(6)" ::: "memory");  // t+1 resident; t+2 in flight
      __builtin_amdgcn_s_barrier();
    } else if (t == 30) {
      asm volatile("s_waitcnt vmcnt(0)" ::: "memory");  // tile 31 resident
      __builtin_amdgcn_s_barrier();
    }
    bi = bi + 1; if (bi == 3) bi = 0;
  }
  __syncthreads();  // all reads of buffers done before z aliases them

  // E1: spill accumulators (full-K fp32 sums) into z
#pragma unroll
  for (int mt = 0; mt < 2; ++mt)
#pragma unroll
    for (int nt = 0; nt < 4; ++nt)
#pragma unroll
      for (int r = 0; r < 4; ++r) {
        int row = wj * 32 + mt * 16 + q * 4 + r;
        int col = we * 64 + nt * 16 + m;
        z[row * 132 + col] = acc[mt][nt][r];
      }
  __syncthreads();

  // E2: z += res + bias
  size_t base = ((size_t)b * NN + j0) * DD;
#pragma unroll
  for (int p = 0; p < 4; ++p) {
    int idx = p * 256 + tid;
    int j = idx >> 4, c8 = (idx & 15) * 8;
    size_t off = (size_t)j * DD + c8;
    const float4* r4 = (const float4*)(res + base + off);
    float4 r0 = r4[0], r1 = r4[1];
    const float4* bi4 = (const float4*)(bias + c8);
    float4 b0 = bi4[0], b1 = bi4[1];
    float* zz = &z[j * 132 + c8];
    zz[0] += r0.x + b0.x; zz[1] += r0.y + b0.y;
    zz[2] += r0.z + b0.z; zz[3] += r0.w + b0.w;
    zz[4] += r1.x + b1.x; zz[5] += r1.y + b1.y;
    zz[6] += r1.z + b1.z; zz[7] += r1.w + b1.w;
  }
  __syncthreads();

  // E3: LN stats (4 threads per row, interleaved reads; 2-way bank = free)
  {
    int j = tid >> 2, s = tid & 3;
    float sum = 0.f, sq = 0.f;
#pragma unroll
    for (int k = 0; k < 32; ++k) {
      float v = z[j * 132 + s + 4 * k];
      sum += v; sq += v * v;
    }
    sum += __shfl_xor(sum, 1); sq += __shfl_xor(sq, 1);
    sum += __shfl_xor(sum, 2); sq += __shfl_xor(sq, 2);
    if (s == 0) {
      float mu = sum * (1.f / 128.f);
      float var = sq * (1.f / 128.f) - mu * mu;
      smu[j] = mu;
      srs[j] = rsqrtf(var + 1e-5f);
    }
  }
  __syncthreads();

  // E4: normalize + ReLU -> outf; keep h in z for gemm1
  {
    int e = tid & 127;
    float g = gamma[e], bt = beta[e];
#pragma unroll
    for (int p = 0; p < 32; ++p) {
      int idx = p * 256 + tid;
      int j = idx >> 7;
      float v = (z[j * 132 + e] - smu[j]) * srs[j] * g + bt;
      v = fmaxf(v, 0.f);
      outf[base + idx] = v;
      z[j * 132 + e] = v;   // same thread, same slot: no race
    }
  }
  if (!doW) return;
  __syncthreads();

  // E5: gemm1 -> tiled hwTnt tile (kt = jt); WTn fragments direct from global
  f32x4 acc2[8];
#pragma unroll
  for (int t = 0; t < 8; ++t)
#pragma unroll
    for (int r = 0; r < 4; ++r) acc2[t][r] = 0.f;
  int il = w * 16 + m;
  const float* hrow = &z[il * 132];
#pragma unroll
  for (int kk = 0; kk < 4; ++kk) {
    int d0 = kk * 32 + q * 8;
    float4 h0 = *(const float4*)(hrow + d0);
    float4 h1 = *(const float4*)(hrow + d0 + 4);
    union { bf16x8 v; unsigned short s[8]; } ub;
    ub.s[0] = f2b(h0.x); ub.s[1] = f2b(h0.y); ub.s[2] = f2b(h0.z); ub.s[3] = f2b(h0.w);
    ub.s[4] = f2b(h1.x); ub.s[5] = f2b(h1.y); ub.s[6] = f2b(h1.z); ub.s[7] = f2b(h1.w);
#pragma unroll
    for (int mt = 0; mt < 8; ++mt) {
      bf16x8 af = *(const bf16x8*)(WTn + (mt * 16 + m) * 128 + d0);
      acc2[mt] = __builtin_amdgcn_mfma_f32_16x16x32_bf16(af, ub.v, acc2[mt], 0, 0, 0);
    }
  }
  unsigned short* dst = hwTnt + ((size_t)b * 32 + jt) * 8192;
#pragma unroll
  for (int mt = 0; mt < 8; ++mt)
#pragma unroll
    for (int r = 0; r < 4; ++r) {
      int e = mt * 16 + q * 4 + r;
      int p = e * 8 + ((il >> 3) ^ (e & 7));
      dst[p * 8 + (il & 7)] = f2b(acc2[mt][r]);
    }
}

extern "C" void kernel_launch(void* const* d_in, const int* in_sizes, int n_in,
                              void* d_out, int out_size, void* d_ws, size_t ws_size,
                              hipStream_t stream) {
  const float* X   = (const float*)d_in[0];
  const float* adj = (const float*)d_in[1];
  const float* Ws  = (const float*)d_in[2];
  const float* bs  = (const float*)d_in[3];
  const float* gms = (const float*)d_in[4];
  const float* bts = (const float*)d_in[5];
  float* out = (float*)d_out;

  // ws: adjTt bf16 (134MB) | hwTt ping-pong bf16 (2 x 8.4MB) | WT bf16 (96KB)
  unsigned short* adjTt = (unsigned short*)d_ws;
  unsigned short* hwT0  = adjTt + (size_t)BB * NN * NN;
  unsigned short* hwT1  = hwT0 + (size_t)BB * DD * NN;
  unsigned short* WT    = hwT1 + (size_t)BB * DD * NN;

  k_pre<<<dim3(291, BB), 256, 0, stream>>>(adj, adjTt, X, Ws, WT, hwT0);
  for (int l = 0; l < 3; ++l) {
    const float* res = (l == 0) ? X : (const float*)out;
    const unsigned short* WTn = WT + (size_t)((l < 2) ? (l + 1) : 0) * DD * DD;
    unsigned short* hin  = (l & 1) ? hwT1 : hwT0;
    unsigned short* hout = (l & 1) ? hwT0 : hwT1;
    k_layer<<<dim3(NN / 64, BB), 256, 0, stream>>>(adjTt, hin, res, bs + l * DD,
                                                   gms + l * DD, bts + l * DD,
                                                   WTn, out, hout, (l < 2) ? 1 : 0);
  }
}